// Round 16
// baseline (77.009 us; speedup 1.0000x reference)
//
#include <hip/hip_runtime.h>

#define NPIX 9216
#define PLANE 82944           // 288*288
#define W4PL 57600            // float4 per (o,i) weight plane

typedef float f4v __attribute__((ext_vector_type(4)));

__global__ __launch_bounds__(192)
void lfk16(const float* __restrict__ lf, const float* __restrict__ wts,
           const float* __restrict__ bias, float* __restrict__ out)
{
    // per-wave private SINGLE-buffered padded weights: [wv][3oc*16px*28]
    __shared__ float ldsW[3][1344];       // 16.13 KB

    const int tid  = threadIdx.x;
    const int wv   = tid >> 6;            // i-split wave 0..2
    const int lane = tid & 63;
    const int px   = lane & 15;
    const int b    = lane >> 4;           // 0..3
    const int bid  = blockIdx.x;
    const int swz  = (bid & 7) * 216 + (bid >> 3);   // bijective XCD swizzle
    const int tile = swz / 3;
    const int og   = swz - tile * 3;
    const int oh   = tile / 6;
    const int tc   = tile - oh * 6;
    const int g    = tile * 16 + px;
    const int ow   = tc * 16 + px;
    const int y0   = oh * 3 - 2;          // pt = pl = 2, no bottom/right pad
    const int x0   = ow * 3 - 2;
    const int xcl  = (x0 < 0) ? 0 : x0;
    const bool xneg = (x0 < 0);           // only px==0 in tc==0 blocks
    const bool tc0  = (tc == 0);          // block-uniform
    const bool oh0  = (oh == 0);          // block-uniform

    const f4v* __restrict__ w4g = (const f4v*)wts;
    float* const myl = &ldsW[wv][0];
    const int i0 = wv * 3;

    // ---- per-wave weight staging: 300 f4 over 64 lanes (5 slots) ----
    f4v sr0, sr1, sr2, sr3, sr4;
    auto stageLoad = [&](int i) {
        #pragma unroll
        for (int j = 0; j < 5; ++j) {
            const int idx = lane + 64 * j;
            if (j < 4 || idx < 300) {
                const int oc  = idx / 100;
                const int rem = idx - oc * 100;
                const f4v v = w4g[(size_t)((og * 3 + oc) * 9 + i) * W4PL + tile * 100 + rem];
                if (j==0) sr0=v; else if (j==1) sr1=v; else if (j==2) sr2=v;
                else if (j==3) sr3=v; else sr4=v;
            }
        }
    };
    auto scatterWrite = [&]() {
        #pragma unroll
        for (int j = 0; j < 5; ++j) {
            const int idx = lane + 64 * j;
            if (j < 4 || idx < 300) {
                const int oc  = idx / 100;
                const int rem = idx - oc * 100;
                const int f0  = rem * 4;
                f4v v;
                if (j==0) v=sr0; else if (j==1) v=sr1; else if (j==2) v=sr2;
                else if (j==3) v=sr3; else v=sr4;
                float vv[4] = {v.x, v.y, v.z, v.w};
                #pragma unroll
                for (int q = 0; q < 4; ++q) {
                    const int f = f0 + q, pd = f / 25, k = f - pd * 25;
                    myl[oc * 448 + pd * 28 + k] = vv[q];
                }
            }
        }
    };

    // ---- patches: ALL 3 c resident per step (single-buffered, 75 regs) ----
    f4v  P[3][5];
    float E[3][5];
    auto loadPall = [&](int i) {
        #pragma unroll
        for (int c = 0; c < 3; ++c) {
            const float* rb = lf + ((b * 9 + i) * 3 + c) * PLANE + xcl;
            #pragma unroll
            for (int kh = 0; kh < 5; ++kh) {
                const int y = y0 + kh;
                if (!oh0 || y >= 0) {         // block-uniform
                    const float* rp = rb + y * 288;
                    __builtin_memcpy(&P[c][kh], rp, 16);
                    E[c][kh] = rp[4];         // x0+4 <= 287: in-bounds
                } else { P[c][kh] = (f4v)0.f; E[c][kh] = 0.f; }
            }
        }
    };

    float acc[3][3] = {{0,0,0},{0,0,0},{0,0,0}};

    // ---- prologue ----
    stageLoad(i0);
    scatterWrite();
    loadPall(i0);

    #pragma unroll 1
    for (int s = 0; s < 3; ++s) {
        const int i = i0 + s;

        // ---- per-oc streamed weights: 7 reads -> 25 transient -> 75 FMAs ----
        #pragma unroll
        for (int oc = 0; oc < 3; ++oc) {
            const float* wr = myl + oc * 448 + px * 28;   // 112B-aligned
            const f4v* wq = (const f4v*)wr;
            const f4v u0=wq[0], u1=wq[1], u2=wq[2], u3=wq[3], u4=wq[4], u5=wq[5];
            float wk[25];
            wk[0]=u0.x;  wk[1]=u0.y;  wk[2]=u0.z;  wk[3]=u0.w;
            wk[4]=u1.x;  wk[5]=u1.y;  wk[6]=u1.z;  wk[7]=u1.w;
            wk[8]=u2.x;  wk[9]=u2.y;  wk[10]=u2.z; wk[11]=u2.w;
            wk[12]=u3.x; wk[13]=u3.y; wk[14]=u3.z; wk[15]=u3.w;
            wk[16]=u4.x; wk[17]=u4.y; wk[18]=u4.z; wk[19]=u4.w;
            wk[20]=u5.x; wk[21]=u5.y; wk[22]=u5.z; wk[23]=u5.w;
            wk[24]=wr[24];

            if (oc == 2 && s < 2) stageLoad(i + 1);   // short sr live range

            #pragma unroll
            for (int c = 0; c < 3; ++c) {
                #pragma unroll
                for (int kh = 0; kh < 5; ++kh) {
                    const f4v a = P[c][kh]; const float e = E[c][kh];
                    float q0,q1,q2,q3,q4;
                    if (tc0) {
                        q0 = xneg ? 0.f : a.x;  q1 = xneg ? 0.f : a.y;
                        q2 = xneg ? a.x : a.z;  q3 = xneg ? a.y : a.w;
                        q4 = xneg ? a.z : e;
                    } else { q0=a.x; q1=a.y; q2=a.z; q3=a.w; q4=e; }
                    acc[oc][c] = fmaf(wk[kh*5+0], q0, acc[oc][c]);
                    acc[oc][c] = fmaf(wk[kh*5+1], q1, acc[oc][c]);
                    acc[oc][c] = fmaf(wk[kh*5+2], q2, acc[oc][c]);
                    acc[oc][c] = fmaf(wk[kh*5+3], q3, acc[oc][c]);
                    acc[oc][c] = fmaf(wk[kh*5+4], q4, acc[oc][c]);
                }
            }
        }

        if (s < 2) {
            scatterWrite();      // after last read of this step; in-order DS = safe
            loadPall(i + 1);     // after last FMA use of P; covered by boundary
        }
    }

    // ---- cross-wave reduction (single barrier) ----
    if (wv != 0) {
        #pragma unroll
        for (int oc = 0; oc < 3; ++oc)
            #pragma unroll
            for (int c = 0; c < 3; ++c)
                myl[lane * 9 + oc * 3 + c] = acc[oc][c];
    }
    __syncthreads();

    if (wv == 0) {
        #pragma unroll
        for (int oc = 0; oc < 3; ++oc)
            #pragma unroll
            for (int c = 0; c < 3; ++c)
                acc[oc][c] += ldsW[1][lane * 9 + oc * 3 + c]
                            + ldsW[2][lane * 9 + oc * 3 + c];
        #pragma unroll
        for (int oc = 0; oc < 3; ++oc) {
            const int o = og * 3 + oc;
            const float bo = bias[o * NPIX + g];
            #pragma unroll
            for (int c = 0; c < 3; ++c) {
                float v = acc[oc][c] + bo;
                v = fminf(fmaxf(v, 0.f), 1.f);
                out[((b * 9 + o) * 3 + c) * NPIX + g] = v;
            }
        }
    }
}

extern "C" void kernel_launch(void* const* d_in, const int* in_sizes, int n_in,
                              void* d_out, int out_size, void* d_ws, size_t ws_size,
                              hipStream_t stream) {
    const float* lf   = (const float*)d_in[0];
    const float* wts  = (const float*)d_in[1];
    const float* bias = (const float*)d_in[2];
    float* out = (float*)d_out;
    (void)d_ws; (void)ws_size; (void)in_sizes; (void)n_in; (void)out_size;

    dim3 grid(576 * 3);     // 1728 blocks x 3 waves (i-split)
    dim3 block(192);
    lfk16<<<grid, block, 0, stream>>>(lf, wts, bias, out);
}